// Round 1
// baseline (364.468 us; speedup 1.0000x reference)
//
#include <hip/hip_runtime.h>

// RWKV6 TimeMix on MI355X — 7-kernel pipeline:
//   K0 prep_w     : 5 weight matrices fp32 -> bf16
//   K1 prep_mix   : token-shift mix -> xr,xk,xv,xw (bf16)
//   K2 gemm4_bt   : 4x MFMA GEMM (4096x1024x1024) + fused activations -> r,k,v,w (fp32)
//   K3 scan_intra : chunked (C=64) local scan -> o_intra, rd, U_c, D_c
//   K4 state_prop : S_{c+1} = D_c*S_c + U_c (in-place, U slot becomes chunk-initial S_c)
//   K5 inter_ln   : o += rd@S_c, group-LN, *r, -> bf16
//   K6 gemm_out   : MFMA GEMM -> d_out (fp32)
//
// Shapes: B=4, T=1024, D=1024, H=16, DH=64. Chunks: NC=16, C=64.

typedef unsigned short u16;
typedef unsigned int   u32;

typedef __attribute__((ext_vector_type(8))) __bf16 bf16x8;
typedef __attribute__((ext_vector_type(4))) float   f32x4;

#define MB (1u << 20)

__device__ __forceinline__ u16 f2bf(float f) {
  u32 u = __builtin_bit_cast(u32, f);
  u += 0x7FFFu + ((u >> 16) & 1u);   // RNE; inputs are finite
  return (u16)(u >> 16);
}
__device__ __forceinline__ u32 pack2(float a, float b) {
  return (u32)f2bf(a) | ((u32)f2bf(b) << 16);
}

// ---------------- K0: weights fp32 -> bf16 (5 x 1M elements, 2-wide) --------
__global__ __launch_bounds__(256) void prep_w(
    const float* __restrict__ w0, const float* __restrict__ w1,
    const float* __restrict__ w2, const float* __restrict__ w3,
    const float* __restrict__ w4, u32* __restrict__ out) {
  int idx = blockIdx.x * 256 + threadIdx.x;   // pair index, 5*524288 total
  int m = idx >> 19;                          // matrix id (uniform per block)
  int l = idx & 524287;
  const float* src = (m == 0) ? w0 : (m == 1) ? w1 : (m == 2) ? w2 : (m == 3) ? w3 : w4;
  float2 v = *(const float2*)(src + (size_t)l * 2);
  out[idx] = pack2(v.x, v.y);
}

// ---------------- K1: token-shift mix -> bf16 (2-wide) ----------------------
__global__ __launch_bounds__(256) void prep_mix(
    const float* __restrict__ x,
    const float* __restrict__ tmr, const float* __restrict__ tmk,
    const float* __restrict__ tmv, const float* __restrict__ tmw,
    u32* __restrict__ xr, u32* __restrict__ xk,
    u32* __restrict__ xv, u32* __restrict__ xw) {
  int idx = blockIdx.x * 256 + threadIdx.x;   // pair index over 4*1024*512
  int t  = (idx >> 9) & 1023;
  int d0 = (idx & 511) * 2;
  size_t e = (size_t)idx * 2;
  float2 xc = *(const float2*)(x + e);
  float2 xp = make_float2(0.f, 0.f);
  if (t > 0) xp = *(const float2*)(x + e - 1024);
  float2 tm;
  tm = *(const float2*)(tmr + d0);
  xr[idx] = pack2(tm.x * xc.x + (1.f - tm.x) * xp.x, tm.y * xc.y + (1.f - tm.y) * xp.y);
  tm = *(const float2*)(tmk + d0);
  xk[idx] = pack2(tm.x * xc.x + (1.f - tm.x) * xp.x, tm.y * xc.y + (1.f - tm.y) * xp.y);
  tm = *(const float2*)(tmv + d0);
  xv[idx] = pack2(tm.x * xc.x + (1.f - tm.x) * xp.x, tm.y * xc.y + (1.f - tm.y) * xp.y);
  tm = *(const float2*)(tmw + d0);
  xw[idx] = pack2(tm.x * xc.x + (1.f - tm.x) * xp.x, tm.y * xc.y + (1.f - tm.y) * xp.y);
}

// ---------------- GEMM core: C[m][n] = sum_k A[m][k]*W[n][k] ----------------
// A: 4096x1024 bf16 row-major. W: 1024x1024 bf16 row-major (NT / "B^T" form).
// Tile 128x128xBK32, 256 threads (4 waves, each a 64x64 quadrant, 4x4 MFMA tiles).
// ACT: 0 = none, 1 = sigmoid, 2 = -softplus(-z)-1e-4.
template <int ACT>
__device__ __forceinline__ void gemm_core(
    const u16* __restrict__ A, const u16* __restrict__ W, float* __restrict__ O,
    u16* Asm, u16* Bsm) {
  int tid = threadIdx.x;
  int m0 = blockIdx.y * 128, n0 = blockIdx.x * 128;
  int wave = tid >> 6, lane = tid & 63;
  int wm = (wave >> 1) * 64, wn = (wave & 1) * 64;
  int r16 = lane & 15, quad = lane >> 4;

  f32x4 acc[4][4] = {};

  int arow = tid >> 2;          // 0..63
  int acol = (tid & 3) * 8;     // 0,8,16,24  (bf16 elements)
  const u16* Ag = A + (size_t)(m0 + arow) * 1024 + acol;
  const u16* Bg = W + (size_t)(n0 + arow) * 1024 + acol;

  for (int k0 = 0; k0 < 1024; k0 += 32) {
    // stage A/B tiles (128x32 bf16 each), 16B per thread per quarter
    *(float4*)&Asm[arow * 32 + acol]        = *(const float4*)(Ag + k0);
    *(float4*)&Asm[(arow + 64) * 32 + acol] = *(const float4*)(Ag + 64 * 1024 + k0);
    *(float4*)&Bsm[arow * 32 + acol]        = *(const float4*)(Bg + k0);
    *(float4*)&Bsm[(arow + 64) * 32 + acol] = *(const float4*)(Bg + 64 * 1024 + k0);
    __syncthreads();

    bf16x8 af[4], bfm[4];
#pragma unroll
    for (int mt = 0; mt < 4; ++mt)
      af[mt] = *(const bf16x8*)&Asm[(wm + mt * 16 + r16) * 32 + quad * 8];
#pragma unroll
    for (int nt = 0; nt < 4; ++nt)
      bfm[nt] = *(const bf16x8*)&Bsm[(wn + nt * 16 + r16) * 32 + quad * 8];
#pragma unroll
    for (int mt = 0; mt < 4; ++mt)
#pragma unroll
      for (int nt = 0; nt < 4; ++nt)
        acc[mt][nt] = __builtin_amdgcn_mfma_f32_16x16x32_bf16(af[mt], bfm[nt], acc[mt][nt], 0, 0, 0);
    __syncthreads();
  }

  // epilogue: C/D layout col=lane&15, row=quad*4+reg  [verified m89/m91]
#pragma unroll
  for (int mt = 0; mt < 4; ++mt) {
#pragma unroll
    for (int nt = 0; nt < 4; ++nt) {
#pragma unroll
      for (int rg = 0; rg < 4; ++rg) {
        int row = m0 + wm + mt * 16 + quad * 4 + rg;
        int col = n0 + wn + nt * 16 + r16;
        float v = acc[mt][nt][rg];
        if (ACT == 1) v = 1.f / (1.f + __expf(-v));
        else if (ACT == 2) v = -(fmaxf(-v, 0.f) + log1pf(expf(-fabsf(v)))) - 1e-4f;
        O[(size_t)row * 1024 + col] = v;
      }
    }
  }
}

// K2: all four projection GEMMs in one launch (grid.z selects matrix)
__global__ __launch_bounds__(256) void gemm4_bt(
    const u16* __restrict__ xr, const u16* __restrict__ xk,
    const u16* __restrict__ xv, const u16* __restrict__ xw,
    const u16* __restrict__ Wr, const u16* __restrict__ Wk,
    const u16* __restrict__ Wv, const u16* __restrict__ Ww,
    float* __restrict__ r, float* __restrict__ k,
    float* __restrict__ v, float* __restrict__ w) {
  __shared__ __align__(16) u16 Asm[128 * 32];
  __shared__ __align__(16) u16 Bsm[128 * 32];
  switch (blockIdx.z) {
    case 0:  gemm_core<1>(xr, Wr, r, Asm, Bsm); break;   // r = sigmoid
    case 1:  gemm_core<0>(xk, Wk, k, Asm, Bsm); break;
    case 2:  gemm_core<0>(xv, Wv, v, Asm, Bsm); break;
    default: gemm_core<2>(xw, Ww, w, Asm, Bsm); break;   // w = -softplus(-z)-1e-4
  }
}

// K6: output GEMM
__global__ __launch_bounds__(256) void gemm_out(
    const u16* __restrict__ A, const u16* __restrict__ W, float* __restrict__ O) {
  __shared__ __align__(16) u16 Asm[128 * 32];
  __shared__ __align__(16) u16 Bsm[128 * 32];
  gemm_core<0>(A, W, O, Asm, Bsm);
}

// ---------------- K3: intra-chunk scan --------------------------------------
// Block = (chunk c, b*16+h), 256 threads = 4 i-groups x 64 j.
// Wave roles for staging: w0 loads r (and maintains decay d, writes rd),
// w1 loads k (writes k and exp(u+k)), w2 loads v, w3 loads w (writes exp(w)).
// Thread (ig,j) owns s[i][j] for i in [ig*16, ig*16+16).
__global__ __launch_bounds__(256) void scan_intra(
    const float* __restrict__ rb, const float* __restrict__ kb,
    const float* __restrict__ vb, const float* __restrict__ wb,
    const float* __restrict__ u,
    float* __restrict__ o, float* __restrict__ rd,
    float* __restrict__ U, float* __restrict__ Dc) {
  int c = blockIdx.x, bh = blockIdx.y;
  int b = bh >> 4, h = bh & 15;
  int tid = threadIdx.x, ig = tid >> 6, j = tid & 63;

  __shared__ __align__(16) float combo[64][4];  // per-i: r, k, exp(u+k), exp(w)
  __shared__ float vs[64];
  __shared__ float part[4][64];

  float s[16];
#pragma unroll
  for (int ii = 0; ii < 16; ++ii) s[ii] = 0.f;

  size_t base = ((size_t)(b * 1024 + c * 64)) * 1024 + h * 64 + j;
  const float* src = (ig == 0) ? rb : (ig == 1) ? kb : (ig == 2) ? vb : wb;
  float dloc = 1.0f;
  float uval = (ig == 1) ? u[h * 64 + j] : 0.f;
  float pre = src[base];                         // prefetch t=0

  for (int t = 0; t < 64; ++t) {
    float val = pre;
    if (t < 63) pre = src[base + (size_t)(t + 1) * 1024];  // prefetch next step
    if (ig == 0) { combo[j][0] = val; rd[base + (size_t)t * 1024] = val * dloc; }
    else if (ig == 1) { combo[j][1] = val; combo[j][2] = __expf(uval + val); }
    else if (ig == 2) { vs[j] = val; }
    else { combo[j][3] = __expf(val); }
    __syncthreads();

    float vj = vs[j];
    float acc = 0.f;
#pragma unroll
    for (int ii = 0; ii < 16; ++ii) {
      float4 cb = *(const float4*)&combo[ig * 16 + ii][0];  // broadcast b128
      float tmp = fmaf(cb.z, vj, s[ii]);     // s + exp(u+k)*v
      acc = fmaf(cb.x, tmp, acc);            // += r * (...)
      s[ii] = fmaf(cb.w, s[ii], cb.y * vj);  // s = exp(w)*s + k*v
    }
    part[ig][j] = acc;
    if (ig == 0) dloc *= combo[j][3];        // decay update (combo stable here)
    __syncthreads();
    if (ig == 0)
      o[base + (size_t)t * 1024] = part[0][j] + part[1][j] + part[2][j] + part[3][j];
  }

  float* Ug = U + (size_t)(bh * 16 + c) * 4096;
#pragma unroll
  for (int ii = 0; ii < 16; ++ii) Ug[(ig * 16 + ii) * 64 + j] = s[ii];
  if (ig == 0) Dc[(bh * 16 + c) * 64 + j] = dloc;
}

// ---------------- K4: chunk-state propagation (in-place) --------------------
// U slot c becomes S_c (state at chunk start); S_0 = 0.
__global__ __launch_bounds__(256) void state_prop(
    float* __restrict__ U, const float* __restrict__ Dc) {
  int bh = blockIdx.x, tid = threadIdx.x;
  float acc[16];
#pragma unroll
  for (int q = 0; q < 16; ++q) acc[q] = 0.f;
  for (int c = 0; c < 16; ++c) {
    float* Ug = U + (size_t)(bh * 16 + c) * 4096;
    const float* Dg = Dc + (bh * 16 + c) * 64;
    float uv[16], dv[16];
#pragma unroll
    for (int q = 0; q < 16; ++q) {
      int e = tid + q * 256;
      uv[q] = Ug[e];
      dv[q] = Dg[e >> 6];
    }
#pragma unroll
    for (int q = 0; q < 16; ++q) {
      int e = tid + q * 256;
      Ug[e] = acc[q];                       // write S_c
      acc[q] = fmaf(dv[q], acc[q], uv[q]);  // S_{c+1} = D_c*S_c + U_c
    }
  }
}

// ---------------- K5: inter-chunk output + group-LN + r-gate -> bf16 --------
__global__ __launch_bounds__(256) void inter_ln(
    const float* __restrict__ o, const float* __restrict__ rd,
    const float* __restrict__ rb, const float* __restrict__ S,
    const float* __restrict__ lnw, const float* __restrict__ lnb,
    u16* __restrict__ oh) {
  int c = blockIdx.x, bh = blockIdx.y;
  int b = bh >> 4, h = bh & 15;
  int tid = threadIdx.x;
  __shared__ float Sl[64 * 64];
  __shared__ float rdl[64 * 64];
  const float* Sg = S + (size_t)(bh * 16 + c) * 4096;
  size_t rbase = ((size_t)(b * 1024 + c * 64)) * 1024 + h * 64;
#pragma unroll
  for (int q = 0; q < 16; ++q) { int e = tid + q * 256; Sl[e] = Sg[e]; }
#pragma unroll
  for (int q = 0; q < 16; ++q) {
    int e = tid + q * 256; int t = e >> 6, i = e & 63;
    rdl[e] = rd[rbase + (size_t)t * 1024 + i];
  }
  __syncthreads();
  int wave = tid >> 6, lane = tid & 63;
  float lw = lnw[lane], lb = lnb[lane];
  for (int it = 0; it < 16; ++it) {
    int t = it * 4 + wave;
    size_t gidx = rbase + (size_t)t * 1024 + lane;
    float acc = o[gidx];
#pragma unroll 8
    for (int i = 0; i < 64; ++i)
      acc = fmaf(rdl[t * 64 + i], Sl[i * 64 + lane], acc);  // + rd @ S_c
    // group-LN over the 64 lanes (head dim)
    float s1 = acc, s2 = acc * acc;
#pragma unroll
    for (int m = 1; m < 64; m <<= 1) {
      s1 += __shfl_xor(s1, m, 64);
      s2 += __shfl_xor(s2, m, 64);
    }
    float mu = s1 * (1.f / 64.f);
    float var = s2 * (1.f / 64.f) - mu * mu;
    float nv = (acc - mu) * rsqrtf(var + 1e-5f);
    float val = (nv * lw + lb) * rb[gidx];
    oh[gidx] = f2bf(val);
  }
}

// ---------------- launch -----------------------------------------------------
extern "C" void kernel_launch(void* const* d_in, const int* in_sizes, int n_in,
                              void* d_out, int out_size, void* d_ws, size_t ws_size,
                              hipStream_t stream) {
  const float* x    = (const float*)d_in[0];
  const float* W_r  = (const float*)d_in[1];
  const float* W_k  = (const float*)d_in[2];
  const float* W_v  = (const float*)d_in[3];
  const float* W_w  = (const float*)d_in[4];
  const float* W_o  = (const float*)d_in[5];
  const float* u    = (const float*)d_in[6];
  const float* tm_r = (const float*)d_in[7];
  const float* tm_k = (const float*)d_in[8];
  const float* tm_v = (const float*)d_in[9];
  const float* tm_w = (const float*)d_in[10];
  const float* ln_w = (const float*)d_in[11];
  const float* ln_b = (const float*)d_in[12];
  float* out = (float*)d_out;

  char* ws = (char*)d_ws;
  // bf16 mixed inputs (dead after K2; region reused for o/rd)
  u16* xr = (u16*)(ws + (size_t)0 * MB);
  u16* xk = (u16*)(ws + (size_t)8 * MB);
  u16* xv = (u16*)(ws + (size_t)16 * MB);
  u16* xw = (u16*)(ws + (size_t)24 * MB);
  u16* Wb = (u16*)(ws + (size_t)32 * MB);   // 5 x 2MB: Wr,Wk,Wv,Ww,Wo
  u16* Wrb = Wb;
  u16* Wkb = (u16*)(ws + (size_t)34 * MB);
  u16* Wvb = (u16*)(ws + (size_t)36 * MB);
  u16* Wwb = (u16*)(ws + (size_t)38 * MB);
  u16* Wob = (u16*)(ws + (size_t)40 * MB);
  float* rbuf = (float*)(ws + (size_t)48 * MB);
  float* kbuf = (float*)(ws + (size_t)64 * MB);
  float* vbuf = (float*)(ws + (size_t)80 * MB);
  float* wbuf = (float*)(ws + (size_t)96 * MB);
  float* Ubuf  = (float*)(ws + (size_t)112 * MB);  // 16MB (also holds S_c after K4)
  float* Dcbuf = (float*)(ws + (size_t)128 * MB);  // 256KB
  u16*   ohbuf = (u16*)(ws + (size_t)129 * MB);    // 8MB
  float* obuf  = (float*)(ws + (size_t)0 * MB);    // alias xr/xk (safe: K3 after K2)
  float* rdbuf = (float*)(ws + (size_t)16 * MB);   // alias xv/xw

  prep_w<<<10240, 256, 0, stream>>>(W_r, W_k, W_v, W_w, W_o, (u32*)Wb);
  prep_mix<<<8192, 256, 0, stream>>>(x, tm_r, tm_k, tm_v, tm_w,
                                     (u32*)xr, (u32*)xk, (u32*)xv, (u32*)xw);
  gemm4_bt<<<dim3(8, 32, 4), 256, 0, stream>>>(xr, xk, xv, xw,
                                               Wrb, Wkb, Wvb, Wwb,
                                               rbuf, kbuf, vbuf, wbuf);
  scan_intra<<<dim3(16, 64), 256, 0, stream>>>(rbuf, kbuf, vbuf, wbuf, u,
                                               obuf, rdbuf, Ubuf, Dcbuf);
  state_prop<<<64, 256, 0, stream>>>(Ubuf, Dcbuf);
  inter_ln<<<dim3(16, 64), 256, 0, stream>>>(obuf, rdbuf, rbuf, Ubuf,
                                             ln_w, ln_b, ohbuf);
  gemm_out<<<dim3(8, 32, 1), 256, 0, stream>>>(ohbuf, Wob, out);
}

// Round 2
// 327.548 us; speedup vs baseline: 1.1127x; 1.1127x over previous
//
#include <hip/hip_runtime.h>

// RWKV6 TimeMix on MI355X — 7-kernel pipeline (R2: global_load_lds GEMM,
// swizzled LDS, 1-barrier scan, parallel state_prop):
//   K0 prep_w     : 5 weight matrices fp32 -> bf16
//   K1 prep_mix   : token-shift mix -> xr,xk,xv,xw (bf16)
//   K2 gemm4_bt   : 4x MFMA GEMM (4096x1024x1024) + fused activations -> r,k,v,w (fp32)
//   K3 scan_intra : chunked (C=64) local scan -> o_intra, rd, U_c, D_c
//   K4 state_prop : S_{c+1} = D_c*S_c + U_c (per-element parallel over bh*4096)
//   K5 inter_ln   : o += rd@S_c, group-LN, *r, -> bf16
//   K6 gemm_out   : MFMA GEMM -> d_out (fp32)
//
// Shapes: B=4, T=1024, D=1024, H=16, DH=64. Chunks: NC=16, C=64.

typedef unsigned short u16;
typedef unsigned int   u32;

typedef __attribute__((ext_vector_type(8))) __bf16 bf16x8;
typedef __attribute__((ext_vector_type(4))) float   f32x4;

#define MB (1u << 20)

#define LDS_PTR(p) ((__attribute__((address_space(3))) void*)(p))
#define GLB_PTR(p) ((const __attribute__((address_space(1))) void*)(p))

__device__ __forceinline__ u16 f2bf(float f) {
  u32 u = __builtin_bit_cast(u32, f);
  u += 0x7FFFu + ((u >> 16) & 1u);   // RNE; inputs are finite
  return (u16)(u >> 16);
}
__device__ __forceinline__ u32 pack2(float a, float b) {
  return (u32)f2bf(a) | ((u32)f2bf(b) << 16);
}

// ---------------- K0: weights fp32 -> bf16 (5 x 1M elements, 2-wide) --------
__global__ __launch_bounds__(256) void prep_w(
    const float* __restrict__ w0, const float* __restrict__ w1,
    const float* __restrict__ w2, const float* __restrict__ w3,
    const float* __restrict__ w4, u32* __restrict__ out) {
  int idx = blockIdx.x * 256 + threadIdx.x;   // pair index, 5*524288 total
  int m = idx >> 19;                          // matrix id (uniform per block)
  int l = idx & 524287;
  const float* src = (m == 0) ? w0 : (m == 1) ? w1 : (m == 2) ? w2 : (m == 3) ? w3 : w4;
  float2 v = *(const float2*)(src + (size_t)l * 2);
  out[idx] = pack2(v.x, v.y);
}

// ---------------- K1: token-shift mix -> bf16 (2-wide) ----------------------
__global__ __launch_bounds__(256) void prep_mix(
    const float* __restrict__ x,
    const float* __restrict__ tmr, const float* __restrict__ tmk,
    const float* __restrict__ tmv, const float* __restrict__ tmw,
    u32* __restrict__ xr, u32* __restrict__ xk,
    u32* __restrict__ xv, u32* __restrict__ xw) {
  int idx = blockIdx.x * 256 + threadIdx.x;   // pair index over 4*1024*512
  int t  = (idx >> 9) & 1023;
  int d0 = (idx & 511) * 2;
  size_t e = (size_t)idx * 2;
  float2 xc = *(const float2*)(x + e);
  float2 xp = make_float2(0.f, 0.f);
  if (t > 0) xp = *(const float2*)(x + e - 1024);
  float2 tm;
  tm = *(const float2*)(tmr + d0);
  xr[idx] = pack2(tm.x * xc.x + (1.f - tm.x) * xp.x, tm.y * xc.y + (1.f - tm.y) * xp.y);
  tm = *(const float2*)(tmk + d0);
  xk[idx] = pack2(tm.x * xc.x + (1.f - tm.x) * xp.x, tm.y * xc.y + (1.f - tm.y) * xp.y);
  tm = *(const float2*)(tmv + d0);
  xv[idx] = pack2(tm.x * xc.x + (1.f - tm.x) * xp.x, tm.y * xc.y + (1.f - tm.y) * xp.y);
  tm = *(const float2*)(tmw + d0);
  xw[idx] = pack2(tm.x * xc.x + (1.f - tm.x) * xp.x, tm.y * xc.y + (1.f - tm.y) * xp.y);
}

// ---------------- GEMM core: C[m][n] = sum_k A[m][k]*W[n][k] ----------------
// A: 4096x1024 bf16 row-major. W: 1024x1024 bf16 row-major (NT form).
// Tile 128x128xBK32, 256 threads (4 waves, each a 64x64 quadrant, 4x4 MFMA).
// Staging via global_load_lds width=16 (direct HBM->LDS, m97 structure).
// LDS layout XOR-swizzled: slot (row, c) holds global chunk c ^ ((row>>1)&3)
// -> fragment ds_read_b128 lands 2 lanes/bank-group (free) instead of 8-way.
// ACT: 0 = none, 1 = sigmoid, 2 = -softplus(-z)-1e-4.
template <int ACT>
__device__ __forceinline__ void gemm_core(
    const u16* __restrict__ A, const u16* __restrict__ W, float* __restrict__ O,
    u16* Asm, u16* Bsm) {
  int tid = threadIdx.x;
  int m0 = blockIdx.y * 128, n0 = blockIdx.x * 128;
  int wave = tid >> 6, lane = tid & 63;
  int wm = (wave >> 1) * 64, wn = (wave & 1) * 64;
  int r16 = lane & 15, quad = lane >> 4;

  f32x4 acc[4][4] = {};

  // ---- staging addresses: wave w stages tile rows [w*32, w*32+32), 2 insts
  // of 1KB each per matrix. Lane l covers (row = base + (l>>2), chunk c=l&3),
  // fetching swizzled global chunk q = c ^ ((row>>1)&3).
  int srow0 = wave * 32 + (lane >> 2);       // inst-0 row in tile
  int srow1 = srow0 + 16;                    // inst-1 row
  int c4    = lane & 3;
  int q0 = c4 ^ ((srow0 >> 1) & 3);
  int q1 = c4 ^ ((srow1 >> 1) & 3);
  const u16* Ag0 = A + (size_t)(m0 + srow0) * 1024 + q0 * 8;
  const u16* Ag1 = A + (size_t)(m0 + srow1) * 1024 + q1 * 8;
  const u16* Bg0 = W + (size_t)(n0 + srow0) * 1024 + q0 * 8;
  const u16* Bg1 = W + (size_t)(n0 + srow1) * 1024 + q1 * 8;
  u16* ldsA0 = Asm + wave * 1024;            // u16 elems: wave*2048 bytes
  u16* ldsA1 = Asm + wave * 1024 + 512;
  u16* ldsB0 = Bsm + wave * 1024;
  u16* ldsB1 = Bsm + wave * 1024 + 512;

  // ---- fragment read offsets (u16 elems), swizzle-inverted per row
  int aoff[4], boff[4];
#pragma unroll
  for (int mt = 0; mt < 4; ++mt) {
    int r = wm + mt * 16 + r16;
    aoff[mt] = r * 32 + (quad ^ ((r >> 1) & 3)) * 8;
  }
#pragma unroll
  for (int nt = 0; nt < 4; ++nt) {
    int r = wn + nt * 16 + r16;
    boff[nt] = r * 32 + (quad ^ ((r >> 1) & 3)) * 8;
  }

  for (int k0 = 0; k0 < 1024; k0 += 32) {
    __syncthreads();   // prior iter's ds_reads done before overwrite
    __builtin_amdgcn_global_load_lds(GLB_PTR(Ag0 + k0), LDS_PTR(ldsA0), 16, 0, 0);
    __builtin_amdgcn_global_load_lds(GLB_PTR(Ag1 + k0), LDS_PTR(ldsA1), 16, 0, 0);
    __builtin_amdgcn_global_load_lds(GLB_PTR(Bg0 + k0), LDS_PTR(ldsB0), 16, 0, 0);
    __builtin_amdgcn_global_load_lds(GLB_PTR(Bg1 + k0), LDS_PTR(ldsB1), 16, 0, 0);
    __syncthreads();   // compiler drains vmcnt before s_barrier

    bf16x8 af[4], bfm[4];
#pragma unroll
    for (int mt = 0; mt < 4; ++mt) af[mt] = *(const bf16x8*)&Asm[aoff[mt]];
#pragma unroll
    for (int nt = 0; nt < 4; ++nt) bfm[nt] = *(const bf16x8*)&Bsm[boff[nt]];
#pragma unroll
    for (int mt = 0; mt < 4; ++mt)
#pragma unroll
      for (int nt = 0; nt < 4; ++nt)
        acc[mt][nt] = __builtin_amdgcn_mfma_f32_16x16x32_bf16(af[mt], bfm[nt], acc[mt][nt], 0, 0, 0);
  }

  // epilogue: C/D layout col=lane&15, row=quad*4+reg  [verified m89/m91]
#pragma unroll
  for (int mt = 0; mt < 4; ++mt) {
#pragma unroll
    for (int nt = 0; nt < 4; ++nt) {
#pragma unroll
      for (int rg = 0; rg < 4; ++rg) {
        int row = m0 + wm + mt * 16 + quad * 4 + rg;
        int col = n0 + wn + nt * 16 + r16;
        float v = acc[mt][nt][rg];
        if (ACT == 1) v = 1.f / (1.f + __expf(-v));
        else if (ACT == 2) v = -(fmaxf(-v, 0.f) + log1pf(expf(-fabsf(v)))) - 1e-4f;
        O[(size_t)row * 1024 + col] = v;
      }
    }
  }
}

// K2: all four projection GEMMs in one launch (grid.z selects matrix)
__global__ __launch_bounds__(256) void gemm4_bt(
    const u16* __restrict__ xr, const u16* __restrict__ xk,
    const u16* __restrict__ xv, const u16* __restrict__ xw,
    const u16* __restrict__ Wr, const u16* __restrict__ Wk,
    const u16* __restrict__ Wv, const u16* __restrict__ Ww,
    float* __restrict__ r, float* __restrict__ k,
    float* __restrict__ v, float* __restrict__ w) {
  __shared__ __align__(16) u16 Asm[128 * 32];
  __shared__ __align__(16) u16 Bsm[128 * 32];
  switch (blockIdx.z) {
    case 0:  gemm_core<1>(xr, Wr, r, Asm, Bsm); break;   // r = sigmoid
    case 1:  gemm_core<0>(xk, Wk, k, Asm, Bsm); break;
    case 2:  gemm_core<0>(xv, Wv, v, Asm, Bsm); break;
    default: gemm_core<2>(xw, Ww, w, Asm, Bsm); break;   // w = -softplus(-z)-1e-4
  }
}

// K6: output GEMM
__global__ __launch_bounds__(256) void gemm_out(
    const u16* __restrict__ A, const u16* __restrict__ W, float* __restrict__ O) {
  __shared__ __align__(16) u16 Asm[128 * 32];
  __shared__ __align__(16) u16 Bsm[128 * 32];
  gemm_core<0>(A, W, O, Asm, Bsm);
}

// ---------------- K3: intra-chunk scan (1 barrier / step) -------------------
// Block = (chunk c, b*16+h), 256 threads = 4 i-groups x 64 j.
// Wave roles: w0 loads r (maintains decay d, writes rd), w1 loads k (writes
// k and exp(u+k)), w2 loads v, w3 loads w (writes exp(w)).
// Double-buffered combo/vs/part -> one __syncthreads per t-step.
__global__ __launch_bounds__(256) void scan_intra(
    const float* __restrict__ rb, const float* __restrict__ kb,
    const float* __restrict__ vb, const float* __restrict__ wb,
    const float* __restrict__ u,
    float* __restrict__ o, float* __restrict__ rd,
    float* __restrict__ U, float* __restrict__ Dc) {
  int c = blockIdx.x, bh = blockIdx.y;
  int b = bh >> 4, h = bh & 15;
  int tid = threadIdx.x, ig = tid >> 6, j = tid & 63;

  __shared__ __align__(16) float combo[2][64][4];  // per-i: r, k, exp(u+k), exp(w)
  __shared__ float vsb[2][64];
  __shared__ float part[2][4][64];

  float s[16];
#pragma unroll
  for (int ii = 0; ii < 16; ++ii) s[ii] = 0.f;

  size_t base = ((size_t)(b * 1024 + c * 64)) * 1024 + h * 64 + j;
  const float* src = (ig == 0) ? rb : (ig == 1) ? kb : (ig == 2) ? vb : wb;
  float dloc = 1.0f;
  float uval = (ig == 1) ? u[h * 64 + j] : 0.f;

  // prologue: stage t=0 into buf 0
  {
    float val = src[base];
    if (ig == 0)      combo[0][j][0] = val;
    else if (ig == 1) { combo[0][j][1] = val; combo[0][j][2] = __expf(uval + val); }
    else if (ig == 2) vsb[0][j] = val;
    else              combo[0][j][3] = __expf(val);
  }
  __syncthreads();

  for (int t = 0; t < 64; ++t) {
    int buf = t & 1, nbuf = buf ^ 1;
    // stage t+1 into nbuf (safe: nbuf consumed at t-1, barrier passed)
    if (t < 63) {
      float val = src[base + (size_t)(t + 1) * 1024];
      if (ig == 0)      combo[nbuf][j][0] = val;
      else if (ig == 1) { combo[nbuf][j][1] = val; combo[nbuf][j][2] = __expf(uval + val); }
      else if (ig == 2) vsb[nbuf][j] = val;
      else              combo[nbuf][j][3] = __expf(val);
    }
    if (ig == 0) {
      rd[base + (size_t)t * 1024] = combo[buf][j][0] * dloc;
      dloc *= combo[buf][j][3];
    }
    float vj = vsb[buf][j];
    float acc = 0.f;
#pragma unroll
    for (int ii = 0; ii < 16; ++ii) {
      float4 cb = *(const float4*)&combo[buf][ig * 16 + ii][0];  // broadcast b128
      float tmp = fmaf(cb.z, vj, s[ii]);     // s + exp(u+k)*v
      acc = fmaf(cb.x, tmp, acc);            // += r * (...)
      s[ii] = fmaf(cb.w, s[ii], cb.y * vj);  // s = exp(w)*s + k*v
    }
    part[buf][ig][j] = acc;
    __syncthreads();
    if (ig == 0)
      o[base + (size_t)t * 1024] =
          part[buf][0][j] + part[buf][1][j] + part[buf][2][j] + part[buf][3][j];
  }

  float* Ug = U + (size_t)(bh * 16 + c) * 4096;
#pragma unroll
  for (int ii = 0; ii < 16; ++ii) Ug[(ig * 16 + ii) * 64 + j] = s[ii];
  if (ig == 0) Dc[(bh * 16 + c) * 64 + j] = dloc;
}

// ---------------- K4: chunk-state propagation (per-element parallel) --------
// Each state element scans its 16 chunks independently. U slot c becomes S_c
// (state at chunk start); S_0 = 0. Grid: 64 bh x 16 segments = 1024 blocks.
__global__ __launch_bounds__(256) void state_prop(
    float* __restrict__ U, const float* __restrict__ Dc) {
  int bh  = blockIdx.x >> 4;
  int e   = (blockIdx.x & 15) * 256 + threadIdx.x;  // 0..4095
  int i   = e >> 6;                                 // state row (decay index)
  float acc = 0.f;
  for (int c = 0; c < 16; ++c) {
    float* Ug = U + (size_t)(bh * 16 + c) * 4096 + e;
    float d = Dc[(bh * 16 + c) * 64 + i];
    float uv = *Ug;
    *Ug = acc;                      // write S_c
    acc = fmaf(d, acc, uv);         // S_{c+1} = D_c*S_c + U_c
  }
}

// ---------------- K5: inter-chunk output + group-LN + r-gate -> bf16 --------
__global__ __launch_bounds__(256) void inter_ln(
    const float* __restrict__ o, const float* __restrict__ rd,
    const float* __restrict__ rb, const float* __restrict__ S,
    const float* __restrict__ lnw, const float* __restrict__ lnb,
    u16* __restrict__ oh) {
  int c = blockIdx.x, bh = blockIdx.y;
  int b = bh >> 4, h = bh & 15;
  int tid = threadIdx.x;
  __shared__ float Sl[64 * 64];
  __shared__ float rdl[64 * 64];
  const float* Sg = S + (size_t)(bh * 16 + c) * 4096;
  size_t rbase = ((size_t)(b * 1024 + c * 64)) * 1024 + h * 64;
#pragma unroll
  for (int q = 0; q < 16; ++q) { int e = tid + q * 256; Sl[e] = Sg[e]; }
#pragma unroll
  for (int q = 0; q < 16; ++q) {
    int e = tid + q * 256; int t = e >> 6, i = e & 63;
    rdl[e] = rd[rbase + (size_t)t * 1024 + i];
  }
  __syncthreads();
  int wave = tid >> 6, lane = tid & 63;
  float lw = lnw[lane], lb = lnb[lane];
  for (int it = 0; it < 16; ++it) {
    int t = it * 4 + wave;
    size_t gidx = rbase + (size_t)t * 1024 + lane;
    float acc = o[gidx];
#pragma unroll 8
    for (int i = 0; i < 64; ++i)
      acc = fmaf(rdl[t * 64 + i], Sl[i * 64 + lane], acc);  // + rd @ S_c
    // group-LN over the 64 lanes (head dim)
    float s1 = acc, s2 = acc * acc;
#pragma unroll
    for (int m = 1; m < 64; m <<= 1) {
      s1 += __shfl_xor(s1, m, 64);
      s2 += __shfl_xor(s2, m, 64);
    }
    float mu = s1 * (1.f / 64.f);
    float var = s2 * (1.f / 64.f) - mu * mu;
    float nv = (acc - mu) * rsqrtf(var + 1e-5f);
    float val = (nv * lw + lb) * rb[gidx];
    oh[gidx] = f2bf(val);
  }
}

// ---------------- launch -----------------------------------------------------
extern "C" void kernel_launch(void* const* d_in, const int* in_sizes, int n_in,
                              void* d_out, int out_size, void* d_ws, size_t ws_size,
                              hipStream_t stream) {
  const float* x    = (const float*)d_in[0];
  const float* W_r  = (const float*)d_in[1];
  const float* W_k  = (const float*)d_in[2];
  const float* W_v  = (const float*)d_in[3];
  const float* W_w  = (const float*)d_in[4];
  const float* W_o  = (const float*)d_in[5];
  const float* u    = (const float*)d_in[6];
  const float* tm_r = (const float*)d_in[7];
  const float* tm_k = (const float*)d_in[8];
  const float* tm_v = (const float*)d_in[9];
  const float* tm_w = (const float*)d_in[10];
  const float* ln_w = (const float*)d_in[11];
  const float* ln_b = (const float*)d_in[12];
  float* out = (float*)d_out;

  char* ws = (char*)d_ws;
  // bf16 mixed inputs (dead after K2; region reused for o/rd)
  u16* xr = (u16*)(ws + (size_t)0 * MB);
  u16* xk = (u16*)(ws + (size_t)8 * MB);
  u16* xv = (u16*)(ws + (size_t)16 * MB);
  u16* xw = (u16*)(ws + (size_t)24 * MB);
  u16* Wb = (u16*)(ws + (size_t)32 * MB);   // 5 x 2MB: Wr,Wk,Wv,Ww,Wo
  u16* Wrb = Wb;
  u16* Wkb = (u16*)(ws + (size_t)34 * MB);
  u16* Wvb = (u16*)(ws + (size_t)36 * MB);
  u16* Wwb = (u16*)(ws + (size_t)38 * MB);
  u16* Wob = (u16*)(ws + (size_t)40 * MB);
  float* rbuf = (float*)(ws + (size_t)48 * MB);
  float* kbuf = (float*)(ws + (size_t)64 * MB);
  float* vbuf = (float*)(ws + (size_t)80 * MB);
  float* wbuf = (float*)(ws + (size_t)96 * MB);
  float* Ubuf  = (float*)(ws + (size_t)112 * MB);  // 16MB (also holds S_c after K4)
  float* Dcbuf = (float*)(ws + (size_t)128 * MB);  // 256KB
  u16*   ohbuf = (u16*)(ws + (size_t)129 * MB);    // 8MB
  float* obuf  = (float*)(ws + (size_t)0 * MB);    // alias xr/xk (safe: K3 after K2)
  float* rdbuf = (float*)(ws + (size_t)16 * MB);   // alias xv/xw

  prep_w<<<10240, 256, 0, stream>>>(W_r, W_k, W_v, W_w, W_o, (u32*)Wb);
  prep_mix<<<8192, 256, 0, stream>>>(x, tm_r, tm_k, tm_v, tm_w,
                                     (u32*)xr, (u32*)xk, (u32*)xv, (u32*)xw);
  gemm4_bt<<<dim3(8, 32, 4), 256, 0, stream>>>(xr, xk, xv, xw,
                                               Wrb, Wkb, Wvb, Wwb,
                                               rbuf, kbuf, vbuf, wbuf);
  scan_intra<<<dim3(16, 64), 256, 0, stream>>>(rbuf, kbuf, vbuf, wbuf, u,
                                               obuf, rdbuf, Ubuf, Dcbuf);
  state_prop<<<1024, 256, 0, stream>>>(Ubuf, Dcbuf);
  inter_ln<<<dim3(16, 64), 256, 0, stream>>>(obuf, rdbuf, rbuf, Ubuf,
                                             ln_w, ln_b, ohbuf);
  gemm_out<<<dim3(8, 32, 1), 256, 0, stream>>>(ohbuf, Wob, out);
}

// Round 3
// 320.922 us; speedup vs baseline: 1.1357x; 1.0206x over previous
//
#include <hip/hip_runtime.h>

// RWKV6 TimeMix on MI355X — 7-kernel pipeline (R3: software-pipelined GEMM
// with triple-buffered LDS, raw s_barrier + manual vmcnt — AITER-style
// "never vmcnt(0)" K-loop):
//   K0 prep_w     : 5 weight matrices fp32 -> bf16
//   K1 prep_mix   : token-shift mix -> xr,xk,xv,xw (bf16)
//   K2 gemm4_bt   : 4x MFMA GEMM (4096x1024x1024) + fused activations -> r,k,v,w (fp32)
//   K3 scan_intra : chunked (C=64) local scan -> o_intra, rd, U_c, D_c
//   K4 state_prop : S_{c+1} = D_c*S_c + U_c (per-element parallel)
//   K5 inter_ln   : o += rd@S_c, group-LN, *r, -> bf16
//   K6 gemm_out   : MFMA GEMM -> d_out (fp32)
//
// Shapes: B=4, T=1024, D=1024, H=16, DH=64. Chunks: NC=16, C=64.

typedef unsigned short u16;
typedef unsigned int   u32;

typedef __attribute__((ext_vector_type(8))) __bf16 bf16x8;
typedef __attribute__((ext_vector_type(4))) float   f32x4;

#define MB (1u << 20)

#define LDS_PTR(p) ((__attribute__((address_space(3))) void*)(p))
#define GLB_PTR(p) ((const __attribute__((address_space(1))) void*)(p))

__device__ __forceinline__ u16 f2bf(float f) {
  u32 u = __builtin_bit_cast(u32, f);
  u += 0x7FFFu + ((u >> 16) & 1u);   // RNE; inputs are finite
  return (u16)(u >> 16);
}
__device__ __forceinline__ u32 pack2(float a, float b) {
  return (u32)f2bf(a) | ((u32)f2bf(b) << 16);
}

// ---------------- K0: weights fp32 -> bf16 (5 x 1M elements, 2-wide) --------
__global__ __launch_bounds__(256) void prep_w(
    const float* __restrict__ w0, const float* __restrict__ w1,
    const float* __restrict__ w2, const float* __restrict__ w3,
    const float* __restrict__ w4, u32* __restrict__ out) {
  int idx = blockIdx.x * 256 + threadIdx.x;   // pair index, 5*524288 total
  int m = idx >> 19;                          // matrix id (uniform per block)
  int l = idx & 524287;
  const float* src = (m == 0) ? w0 : (m == 1) ? w1 : (m == 2) ? w2 : (m == 3) ? w3 : w4;
  float2 v = *(const float2*)(src + (size_t)l * 2);
  out[idx] = pack2(v.x, v.y);
}

// ---------------- K1: token-shift mix -> bf16 (2-wide) ----------------------
__global__ __launch_bounds__(256) void prep_mix(
    const float* __restrict__ x,
    const float* __restrict__ tmr, const float* __restrict__ tmk,
    const float* __restrict__ tmv, const float* __restrict__ tmw,
    u32* __restrict__ xr, u32* __restrict__ xk,
    u32* __restrict__ xv, u32* __restrict__ xw) {
  int idx = blockIdx.x * 256 + threadIdx.x;   // pair index over 4*1024*512
  int t  = (idx >> 9) & 1023;
  int d0 = (idx & 511) * 2;
  size_t e = (size_t)idx * 2;
  float2 xc = *(const float2*)(x + e);
  float2 xp = make_float2(0.f, 0.f);
  if (t > 0) xp = *(const float2*)(x + e - 1024);
  float2 tm;
  tm = *(const float2*)(tmr + d0);
  xr[idx] = pack2(tm.x * xc.x + (1.f - tm.x) * xp.x, tm.y * xc.y + (1.f - tm.y) * xp.y);
  tm = *(const float2*)(tmk + d0);
  xk[idx] = pack2(tm.x * xc.x + (1.f - tm.x) * xp.x, tm.y * xc.y + (1.f - tm.y) * xp.y);
  tm = *(const float2*)(tmv + d0);
  xv[idx] = pack2(tm.x * xc.x + (1.f - tm.x) * xp.x, tm.y * xc.y + (1.f - tm.y) * xp.y);
  tm = *(const float2*)(tmw + d0);
  xw[idx] = pack2(tm.x * xc.x + (1.f - tm.x) * xp.x, tm.y * xc.y + (1.f - tm.y) * xp.y);
}

// ---------------- GEMM core: C[m][n] = sum_k A[m][k]*W[n][k] ----------------
// A: Mx1024 bf16 row-major. W: 1024x1024 bf16 row-major (NT form).
// Tile 128x128xBK32, 256 threads (4 waves, each a 64x64 quadrant, 4x4 MFMA).
// Staging: global_load_lds width=16 into a TRIPLE-buffered LDS ring.
// Pipeline: tile i+3 issued at the end of iter i; iter i waits vmcnt(8)
// (its own 4 staging insts landed; the 8 newer stay in flight). Raw
// s_barrier (no compiler vmcnt(0) drain). lgkmcnt(0) before the 2nd
// barrier protects the buffer being re-targeted by the next DMA.
// LDS layout XOR-swizzled: slot (row, c) holds global chunk c ^ ((row>>1)&3)
// -> fragment ds_read_b128 is 2-way (free) instead of 8-way conflicted.
// ACT: 0 = none, 1 = sigmoid, 2 = -softplus(-z)-1e-4.
template <int ACT>
__device__ __forceinline__ void gemm_core(
    const u16* __restrict__ A, const u16* __restrict__ W, float* __restrict__ O,
    u16* Asm, u16* Bsm) {   // each 3*4096 u16 (3 x 8KB)
  int tid = threadIdx.x;
  int m0 = blockIdx.y * 128, n0 = blockIdx.x * 128;
  int wave = tid >> 6, lane = tid & 63;
  int wm = (wave >> 1) * 64, wn = (wave & 1) * 64;
  int r16 = lane & 15, quad = lane >> 4;

  f32x4 acc[4][4] = {};

  // staging: wave w stages tile rows [w*32, w*32+32), lane l -> (row base+(l>>2),
  // chunk c=l&3), fetching swizzled global chunk q = c ^ ((row>>1)&3).
  int srow0 = wave * 32 + (lane >> 2);
  int srow1 = srow0 + 16;
  int c4    = lane & 3;
  int q0 = c4 ^ ((srow0 >> 1) & 3);
  int q1 = c4 ^ ((srow1 >> 1) & 3);
  const u16* Ag0 = A + (size_t)(m0 + srow0) * 1024 + q0 * 8;
  const u16* Ag1 = A + (size_t)(m0 + srow1) * 1024 + q1 * 8;
  const u16* Bg0 = W + (size_t)(n0 + srow0) * 1024 + q0 * 8;
  const u16* Bg1 = W + (size_t)(n0 + srow1) * 1024 + q1 * 8;
  int ldsOff0 = wave * 1024;        // u16 offset within one 8KB buffer
  int ldsOff1 = wave * 1024 + 512;

  // fragment read offsets (u16 elems), swizzle-inverted per row
  int aoff[4], boff[4];
#pragma unroll
  for (int mt = 0; mt < 4; ++mt) {
    int r = wm + mt * 16 + r16;
    aoff[mt] = r * 32 + (quad ^ ((r >> 1) & 3)) * 8;
  }
#pragma unroll
  for (int nt = 0; nt < 4; ++nt) {
    int r = wn + nt * 16 + r16;
    boff[nt] = r * 32 + (quad ^ ((r >> 1) & 3)) * 8;
  }

#define ISSUE_TILE(t, buf)                                                              \
  do {                                                                                  \
    int _o = (buf) * 4096, _k = (t) * 32;                                               \
    __builtin_amdgcn_global_load_lds(GLB_PTR(Ag0 + _k), LDS_PTR(Asm + _o + ldsOff0), 16, 0, 0); \
    __builtin_amdgcn_global_load_lds(GLB_PTR(Ag1 + _k), LDS_PTR(Asm + _o + ldsOff1), 16, 0, 0); \
    __builtin_amdgcn_global_load_lds(GLB_PTR(Bg0 + _k), LDS_PTR(Bsm + _o + ldsOff0), 16, 0, 0); \
    __builtin_amdgcn_global_load_lds(GLB_PTR(Bg1 + _k), LDS_PTR(Bsm + _o + ldsOff1), 16, 0, 0); \
  } while (0)

  // prologue: fill the 3-deep ring
  ISSUE_TILE(0, 0);
  ISSUE_TILE(1, 1);
  ISSUE_TILE(2, 2);

  int cur = 0;
  for (int i = 0; i < 32; ++i) {
    // wait only for tile i's 4 staging insts; newer tiles stay in flight
    if (i < 30)       asm volatile("s_waitcnt vmcnt(8)" ::: "memory");
    else if (i == 30) asm volatile("s_waitcnt vmcnt(4)" ::: "memory");
    else              asm volatile("s_waitcnt vmcnt(0)" ::: "memory");
    __builtin_amdgcn_s_barrier();   // all waves' tile-i data landed

    const u16* As = Asm + cur * 4096;
    const u16* Bs = Bsm + cur * 4096;
    bf16x8 af[4], bfm[4];
#pragma unroll
    for (int mt = 0; mt < 4; ++mt) af[mt] = *(const bf16x8*)&As[aoff[mt]];
#pragma unroll
    for (int nt = 0; nt < 4; ++nt) bfm[nt] = *(const bf16x8*)&Bs[boff[nt]];
#pragma unroll
    for (int mt = 0; mt < 4; ++mt)
#pragma unroll
      for (int nt = 0; nt < 4; ++nt)
        acc[mt][nt] = __builtin_amdgcn_mfma_f32_16x16x32_bf16(af[mt], bfm[nt], acc[mt][nt], 0, 0, 0);

    asm volatile("s_waitcnt lgkmcnt(0)" ::: "memory");  // my ds_reads done
    __builtin_amdgcn_s_barrier();                       // everyone's reads done
    if (i + 3 < 32) ISSUE_TILE(i + 3, cur);             // re-target freed buffer
    cur = (cur == 2) ? 0 : cur + 1;
  }
#undef ISSUE_TILE

  // epilogue: C/D layout col=lane&15, row=quad*4+reg  [verified m89/m91]
#pragma unroll
  for (int mt = 0; mt < 4; ++mt) {
#pragma unroll
    for (int nt = 0; nt < 4; ++nt) {
#pragma unroll
      for (int rg = 0; rg < 4; ++rg) {
        int row = m0 + wm + mt * 16 + quad * 4 + rg;
        int col = n0 + wn + nt * 16 + r16;
        float v = acc[mt][nt][rg];
        if (ACT == 1) v = 1.f / (1.f + __expf(-v));
        else if (ACT == 2) v = -(fmaxf(-v, 0.f) + log1pf(expf(-fabsf(v)))) - 1e-4f;
        O[(size_t)row * 1024 + col] = v;
      }
    }
  }
}

// K2: all four projection GEMMs in one launch (grid.z selects matrix)
__global__ __launch_bounds__(256) void gemm4_bt(
    const u16* __restrict__ xr, const u16* __restrict__ xk,
    const u16* __restrict__ xv, const u16* __restrict__ xw,
    const u16* __restrict__ Wr, const u16* __restrict__ Wk,
    const u16* __restrict__ Wv, const u16* __restrict__ Ww,
    float* __restrict__ r, float* __restrict__ k,
    float* __restrict__ v, float* __restrict__ w) {
  __shared__ __align__(16) u16 Asm[3 * 4096];
  __shared__ __align__(16) u16 Bsm[3 * 4096];
  switch (blockIdx.z) {
    case 0:  gemm_core<1>(xr, Wr, r, Asm, Bsm); break;   // r = sigmoid
    case 1:  gemm_core<0>(xk, Wk, k, Asm, Bsm); break;
    case 2:  gemm_core<0>(xv, Wv, v, Asm, Bsm); break;
    default: gemm_core<2>(xw, Ww, w, Asm, Bsm); break;   // w = -softplus(-z)-1e-4
  }
}

// K6: output GEMM
__global__ __launch_bounds__(256) void gemm_out(
    const u16* __restrict__ A, const u16* __restrict__ W, float* __restrict__ O) {
  __shared__ __align__(16) u16 Asm[3 * 4096];
  __shared__ __align__(16) u16 Bsm[3 * 4096];
  gemm_core<0>(A, W, O, Asm, Bsm);
}

// ---------------- K3: intra-chunk scan (1 barrier / step) -------------------
// Block = (chunk c, b*16+h), 256 threads = 4 i-groups x 64 j.
// Wave roles: w0 loads r (maintains decay d, writes rd), w1 loads k (writes
// k and exp(u+k)), w2 loads v, w3 loads w (writes exp(w)).
// Double-buffered combo/vs/part -> one __syncthreads per t-step.
__global__ __launch_bounds__(256) void scan_intra(
    const float* __restrict__ rb, const float* __restrict__ kb,
    const float* __restrict__ vb, const float* __restrict__ wb,
    const float* __restrict__ u,
    float* __restrict__ o, float* __restrict__ rd,
    float* __restrict__ U, float* __restrict__ Dc) {
  int c = blockIdx.x, bh = blockIdx.y;
  int b = bh >> 4, h = bh & 15;
  int tid = threadIdx.x, ig = tid >> 6, j = tid & 63;

  __shared__ __align__(16) float combo[2][64][4];  // per-i: r, k, exp(u+k), exp(w)
  __shared__ float vsb[2][64];
  __shared__ float part[2][4][64];

  float s[16];
#pragma unroll
  for (int ii = 0; ii < 16; ++ii) s[ii] = 0.f;

  size_t base = ((size_t)(b * 1024 + c * 64)) * 1024 + h * 64 + j;
  const float* src = (ig == 0) ? rb : (ig == 1) ? kb : (ig == 2) ? vb : wb;
  float dloc = 1.0f;
  float uval = (ig == 1) ? u[h * 64 + j] : 0.f;

  // prologue: stage t=0 into buf 0
  {
    float val = src[base];
    if (ig == 0)      combo[0][j][0] = val;
    else if (ig == 1) { combo[0][j][1] = val; combo[0][j][2] = __expf(uval + val); }
    else if (ig == 2) vsb[0][j] = val;
    else              combo[0][j][3] = __expf(val);
  }
  __syncthreads();

  for (int t = 0; t < 64; ++t) {
    int buf = t & 1, nbuf = buf ^ 1;
    // stage t+1 into nbuf (safe: nbuf consumed at t-1, barrier passed)
    if (t < 63) {
      float val = src[base + (size_t)(t + 1) * 1024];
      if (ig == 0)      combo[nbuf][j][0] = val;
      else if (ig == 1) { combo[nbuf][j][1] = val; combo[nbuf][j][2] = __expf(uval + val); }
      else if (ig == 2) vsb[nbuf][j] = val;
      else              combo[nbuf][j][3] = __expf(val);
    }
    if (ig == 0) {
      rd[base + (size_t)t * 1024] = combo[buf][j][0] * dloc;
      dloc *= combo[buf][j][3];
    }
    float vj = vsb[buf][j];
    float acc = 0.f;
#pragma unroll
    for (int ii = 0; ii < 16; ++ii) {
      float4 cb = *(const float4*)&combo[buf][ig * 16 + ii][0];  // broadcast b128
      float tmp = fmaf(cb.z, vj, s[ii]);     // s + exp(u+k)*v
      acc = fmaf(cb.x, tmp, acc);            // += r * (...)
      s[ii] = fmaf(cb.w, s[ii], cb.y * vj);  // s = exp(w)*s + k*v
    }
    part[buf][ig][j] = acc;
    __syncthreads();
    if (ig == 0)
      o[base + (size_t)t * 1024] =
          part[buf][0][j] + part[buf][1][j] + part[buf][2][j] + part[buf][3][j];
  }

  float* Ug = U + (size_t)(bh * 16 + c) * 4096;
#pragma unroll
  for (int ii = 0; ii < 16; ++ii) Ug[(ig * 16 + ii) * 64 + j] = s[ii];
  if (ig == 0) Dc[(bh * 16 + c) * 64 + j] = dloc;
}

// ---------------- K4: chunk-state propagation (per-element parallel) --------
// Each state element scans its 16 chunks independently. U slot c becomes S_c
// (state at chunk start); S_0 = 0. Grid: 64 bh x 16 segments = 1024 blocks.
__global__ __launch_bounds__(256) void state_prop(
    float* __restrict__ U, const float* __restrict__ Dc) {
  int bh  = blockIdx.x >> 4;
  int e   = (blockIdx.x & 15) * 256 + threadIdx.x;  // 0..4095
  int i   = e >> 6;                                 // state row (decay index)
  float acc = 0.f;
  for (int c = 0; c < 16; ++c) {
    float* Ug = U + (size_t)(bh * 16 + c) * 4096 + e;
    float d = Dc[(bh * 16 + c) * 64 + i];
    float uv = *Ug;
    *Ug = acc;                      // write S_c
    acc = fmaf(d, acc, uv);         // S_{c+1} = D_c*S_c + U_c
  }
}

// ---------------- K5: inter-chunk output + group-LN + r-gate -> bf16 --------
__global__ __launch_bounds__(256) void inter_ln(
    const float* __restrict__ o, const float* __restrict__ rd,
    const float* __restrict__ rb, const float* __restrict__ S,
    const float* __restrict__ lnw, const float* __restrict__ lnb,
    u16* __restrict__ oh) {
  int c = blockIdx.x, bh = blockIdx.y;
  int b = bh >> 4, h = bh & 15;
  int tid = threadIdx.x;
  __shared__ float Sl[64 * 64];
  __shared__ float rdl[64 * 64];
  const float* Sg = S + (size_t)(bh * 16 + c) * 4096;
  size_t rbase = ((size_t)(b * 1024 + c * 64)) * 1024 + h * 64;
#pragma unroll
  for (int q = 0; q < 16; ++q) { int e = tid + q * 256; Sl[e] = Sg[e]; }
#pragma unroll
  for (int q = 0; q < 16; ++q) {
    int e = tid + q * 256; int t = e >> 6, i = e & 63;
    rdl[e] = rd[rbase + (size_t)t * 1024 + i];
  }
  __syncthreads();
  int wave = tid >> 6, lane = tid & 63;
  float lw = lnw[lane], lb = lnb[lane];
  for (int it = 0; it < 16; ++it) {
    int t = it * 4 + wave;
    size_t gidx = rbase + (size_t)t * 1024 + lane;
    float acc = o[gidx];
#pragma unroll 8
    for (int i = 0; i < 64; ++i)
      acc = fmaf(rdl[t * 64 + i], Sl[i * 64 + lane], acc);  // + rd @ S_c
    // group-LN over the 64 lanes (head dim)
    float s1 = acc, s2 = acc * acc;
#pragma unroll
    for (int m = 1; m < 64; m <<= 1) {
      s1 += __shfl_xor(s1, m, 64);
      s2 += __shfl_xor(s2, m, 64);
    }
    float mu = s1 * (1.f / 64.f);
    float var = s2 * (1.f / 64.f) - mu * mu;
    float nv = (acc - mu) * rsqrtf(var + 1e-5f);
    float val = (nv * lw + lb) * rb[gidx];
    oh[gidx] = f2bf(val);
  }
}

// ---------------- launch -----------------------------------------------------
extern "C" void kernel_launch(void* const* d_in, const int* in_sizes, int n_in,
                              void* d_out, int out_size, void* d_ws, size_t ws_size,
                              hipStream_t stream) {
  const float* x    = (const float*)d_in[0];
  const float* W_r  = (const float*)d_in[1];
  const float* W_k  = (const float*)d_in[2];
  const float* W_v  = (const float*)d_in[3];
  const float* W_w  = (const float*)d_in[4];
  const float* W_o  = (const float*)d_in[5];
  const float* u    = (const float*)d_in[6];
  const float* tm_r = (const float*)d_in[7];
  const float* tm_k = (const float*)d_in[8];
  const float* tm_v = (const float*)d_in[9];
  const float* tm_w = (const float*)d_in[10];
  const float* ln_w = (const float*)d_in[11];
  const float* ln_b = (const float*)d_in[12];
  float* out = (float*)d_out;

  char* ws = (char*)d_ws;
  // bf16 mixed inputs (dead after K2; region reused for o/rd)
  u16* xr = (u16*)(ws + (size_t)0 * MB);
  u16* xk = (u16*)(ws + (size_t)8 * MB);
  u16* xv = (u16*)(ws + (size_t)16 * MB);
  u16* xw = (u16*)(ws + (size_t)24 * MB);
  u16* Wb = (u16*)(ws + (size_t)32 * MB);   // 5 x 2MB: Wr,Wk,Wv,Ww,Wo
  u16* Wrb = Wb;
  u16* Wkb = (u16*)(ws + (size_t)34 * MB);
  u16* Wvb = (u16*)(ws + (size_t)36 * MB);
  u16* Wwb = (u16*)(ws + (size_t)38 * MB);
  u16* Wob = (u16*)(ws + (size_t)40 * MB);
  float* rbuf = (float*)(ws + (size_t)48 * MB);
  float* kbuf = (float*)(ws + (size_t)64 * MB);
  float* vbuf = (float*)(ws + (size_t)80 * MB);
  float* wbuf = (float*)(ws + (size_t)96 * MB);
  float* Ubuf  = (float*)(ws + (size_t)112 * MB);  // 16MB (also holds S_c after K4)
  float* Dcbuf = (float*)(ws + (size_t)128 * MB);  // 256KB
  u16*   ohbuf = (u16*)(ws + (size_t)129 * MB);    // 8MB
  float* obuf  = (float*)(ws + (size_t)0 * MB);    // alias xr/xk (safe: K3 after K2)
  float* rdbuf = (float*)(ws + (size_t)16 * MB);   // alias xv/xw

  prep_w<<<10240, 256, 0, stream>>>(W_r, W_k, W_v, W_w, W_o, (u32*)Wb);
  prep_mix<<<8192, 256, 0, stream>>>(x, tm_r, tm_k, tm_v, tm_w,
                                     (u32*)xr, (u32*)xk, (u32*)xv, (u32*)xw);
  gemm4_bt<<<dim3(8, 32, 4), 256, 0, stream>>>(xr, xk, xv, xw,
                                               Wrb, Wkb, Wvb, Wwb,
                                               rbuf, kbuf, vbuf, wbuf);
  scan_intra<<<dim3(16, 64), 256, 0, stream>>>(rbuf, kbuf, vbuf, wbuf, u,
                                               obuf, rdbuf, Ubuf, Dcbuf);
  state_prop<<<1024, 256, 0, stream>>>(Ubuf, Dcbuf);
  inter_ln<<<dim3(16, 64), 256, 0, stream>>>(obuf, rdbuf, rbuf, Ubuf,
                                             ln_w, ln_b, ohbuf);
  gemm_out<<<dim3(8, 32, 1), 256, 0, stream>>>(ohbuf, Wob, out);
}